// Round 1
// baseline (2042.347 us; speedup 1.0000x reference)
//
#include <hip/hip_runtime.h>
#include <hip/hip_bf16.h>

#define T   4096
#define D   256
#define NH  4
#define NN  256   // N (sparse dim)
#define NL  4
#define VV  256   // vocab
#define CI  64    // state/intra chunk
#define NC  (T/CI) // 64

// ---------- helpers ----------

// Row stats for a [16][stride] LDS tile over D=256 columns, 256 threads.
// Thread group: row r = tid>>4, lane l = tid&15 (16 lanes per row, within-wave).
__device__ __forceinline__ void row_stats16(const float* m, int stride, float* mu, float* rs) {
    int r = threadIdx.x >> 4, l = threadIdx.x & 15;
    float s = 0.f, q = 0.f;
    for (int d = l; d < D; d += 16) { float v = m[r * stride + d]; s += v; q += v * v; }
#pragma unroll
    for (int mm = 1; mm < 16; mm <<= 1) { s += __shfl_xor(s, mm); q += __shfl_xor(q, mm); }
    if (l == 0) {
        float mean = s * (1.f / D);
        float var  = q * (1.f / D) - mean * mean;
        mu[r] = mean;
        rs[r] = rsqrtf(fmaxf(var, 0.f) + 1e-5f);
    }
}

// ---------- kernels ----------

// x[t] = LN(embed[idx[t]]) ; one block per row, 256 threads.
__global__ void __launch_bounds__(256) k_embed_ln(const int* __restrict__ idx,
                                                  const float* __restrict__ embed,
                                                  float* __restrict__ x) {
    int t = blockIdx.x, d = threadIdx.x;
    float v = embed[(size_t)idx[t] * D + d];
    __shared__ float red[8];
    float s = v, q = v * v;
#pragma unroll
    for (int m = 1; m < 64; m <<= 1) { s += __shfl_xor(s, m); q += __shfl_xor(q, m); }
    int w = d >> 6;
    if ((d & 63) == 0) { red[w] = s; red[4 + w] = q; }
    __syncthreads();
    s = red[0] + red[1] + red[2] + red[3];
    q = red[4] + red[5] + red[6] + red[7];
    float mu  = s * (1.f / D);
    float var = q * (1.f / D) - mu * mu;
    x[(size_t)t * D + d] = (v - mu) * rsqrtf(fmaxf(var, 0.f) + 1e-5f);
}

// rope tables, once: phase = frac((float)t * freqs[n]) * 2pi  (matches ref f32 op order)
__global__ void k_rope(const float* __restrict__ freqs,
                       float* __restrict__ rcos, float* __restrict__ rsin) {
    int t = blockIdx.x, n = threadIdx.x;
    float p  = (float)t * freqs[n];
    float fr = p - floorf(p);
    float ang = fr * 6.283185307179586f;
    rcos[(size_t)t * NN + n] = cosf(ang);
    rsin[(size_t)t * NN + n] = sinf(ang);
}

// x_sparse = relu(x @ enc[h]) and QR = rope(x_sparse). 32 rows/block, thread = col n.
__global__ void __launch_bounds__(256) k_encode(const float* __restrict__ x,
                                                const float* __restrict__ enc,
                                                const float* __restrict__ rcos,
                                                const float* __restrict__ rsin,
                                                float* __restrict__ xs,
                                                float* __restrict__ qr) {
    int h = blockIdx.y, r0 = blockIdx.x * 32, n = threadIdx.x;
    __shared__ float xls[32][D];
    for (int i = n; i < 32 * D; i += 256) { int ii = i >> 8, kk = i & 255; xls[ii][kk] = x[(size_t)(r0 + ii) * D + kk]; }
    __syncthreads();
    const float* e = enc + (size_t)h * D * NN;
    float acc[32];
#pragma unroll
    for (int r = 0; r < 32; r++) acc[r] = 0.f;
    for (int k = 0; k < D; k++) {
        float w = e[(size_t)k * NN + n];
#pragma unroll
        for (int r = 0; r < 32; r++) acc[r] += xls[r][k] * w;
    }
#pragma unroll
    for (int r = 0; r < 32; r++) {
        int t = r0 + r;
        float v = fmaxf(acc[r], 0.f);
        xs[((size_t)h * T + t) * NN + n] = v;
        float pv  = __shfl_xor(v, 1);            // partner index n^1 (same wave)
        float rot = (n & 1) ? pv : -pv;          // even: -v[n+1], odd: v[n-1]
        qr[((size_t)h * T + t) * NN + n] = v * rcos[(size_t)t * NN + n] + rot * rsin[(size_t)t * NN + n];
    }
}

// per-chunk gram: G[h][c] = QR_c^T @ x_c  [NN x D], 32 n-rows per block, thread = d.
__global__ void __launch_bounds__(256) k_gram(const float* __restrict__ qr,
                                              const float* __restrict__ x,
                                              float* __restrict__ G) {
    int h = blockIdx.z, c = blockIdx.y, n0 = blockIdx.x * 32, d = threadIdx.x;
    __shared__ float qls[CI][32];   // qls[i][r] = QR[c*CI+i][n0+r]
    for (int i = threadIdx.x; i < CI * 32; i += 256) {
        int ii = i >> 5, rr = i & 31;
        qls[ii][rr] = qr[((size_t)h * T + c * CI + ii) * NN + n0 + rr];
    }
    __syncthreads();
    float acc[32];
#pragma unroll
    for (int r = 0; r < 32; r++) acc[r] = 0.f;
    for (int i = 0; i < CI; i++) {
        float xv = x[(size_t)(c * CI + i) * D + d];
#pragma unroll
        for (int r = 0; r < 32; r++) acc[r] += qls[i][r] * xv;
    }
#pragma unroll
    for (int r = 0; r < 32; r++) G[(((size_t)h * NC + c) * NN + n0 + r) * D + d] = acc[r];
}

// exclusive prefix over chunks, in place: G[c] <- sum_{c'<c} G[c']
__global__ void k_prefix(float* __restrict__ G) {
    int h = blockIdx.y;
    int pos = blockIdx.x * 256 + threadIdx.x; // < NN*D
    float run = 0.f;
    for (int c = 0; c < NC; c++) {
        float* p = G + ((size_t)h * NC + c) * NN * D + pos;
        float g = *p; *p = run; run += g;
    }
}

// inter-chunk: ykv = QR @ S_chunk(row). 32 rows/block, thread = d.
__global__ void __launch_bounds__(256) k_inter(const float* __restrict__ qr,
                                               const float* __restrict__ G,
                                               float* __restrict__ ykv) {
    int h = blockIdx.y, r0 = blockIdx.x * 32, c = r0 / CI, d = threadIdx.x;
    __shared__ float qls[32][NN];
    for (int i = threadIdx.x; i < 32 * NN; i += 256) { int ii = i >> 8, kk = i & 255; qls[ii][kk] = qr[((size_t)h * T + r0 + ii) * NN + kk]; }
    __syncthreads();
    const float* S = G + ((size_t)h * NC + c) * NN * D;
    float acc[32];
#pragma unroll
    for (int r = 0; r < 32; r++) acc[r] = 0.f;
    for (int k = 0; k < NN; k++) {
        float sv = S[(size_t)k * D + d];
#pragma unroll
        for (int r = 0; r < 32; r++) acc[r] += qls[r][k] * sv;
    }
#pragma unroll
    for (int r = 0; r < 32; r++) ykv[((size_t)h * T + r0 + r) * D + d] = acc[r];
}

// intra-chunk strict-lower part + LN of the completed rows.
// One block per (h, chunk). P = QR_c @ QR_c^T computed in LDS, then
// ykv[i] += sum_{j<i} P[i][j] * x_c[j], then LayerNorm each row.
__global__ void __launch_bounds__(256) k_intra(const float* __restrict__ qr,
                                               const float* __restrict__ xv,
                                               float* __restrict__ ykv) {
    int h = blockIdx.y, c = blockIdx.x, tid = threadIdx.x;
    __shared__ float q[CI][NN + 1];   // 65.8 KB
    __shared__ float xls[CI][D];      // 65.5 KB
    __shared__ float P[CI][CI + 1];   // 16.6 KB
    __shared__ float smu[16], srs[16];
    for (int i = tid; i < CI * NN; i += 256) { int ii = i >> 8, kk = i & 255; q[ii][kk] = qr[((size_t)h * T + c * CI + ii) * NN + kk]; }
    for (int i = tid; i < CI * D;  i += 256) { int ii = i >> 8, kk = i & 255; xls[ii][kk] = xv[(size_t)(c * CI + ii) * D + kk]; }
    __syncthreads();
    // P via 16x16 thread grid, 4x4 micro-tiles
    int bi = tid >> 4, bj = tid & 15;
    float pr[4][4];
#pragma unroll
    for (int a = 0; a < 4; a++)
#pragma unroll
        for (int b = 0; b < 4; b++) pr[a][b] = 0.f;
    for (int k = 0; k < NN; k++) {
        float qa[4], qb[4];
#pragma unroll
        for (int a = 0; a < 4; a++) qa[a] = q[bi * 4 + a][k];
#pragma unroll
        for (int b = 0; b < 4; b++) qb[b] = q[bj * 4 + b][k];
#pragma unroll
        for (int a = 0; a < 4; a++)
#pragma unroll
            for (int b = 0; b < 4; b++) pr[a][b] += qa[a] * qb[b];
    }
#pragma unroll
    for (int a = 0; a < 4; a++)
#pragma unroll
        for (int b = 0; b < 4; b++) P[bi * 4 + a][bj * 4 + b] = pr[a][b];
    __syncthreads();
    float* scr = &q[0][0];  // q is dead now; reuse as LN scratch (stride NN+1)
    for (int g = 0; g < CI / 16; g++) {
        float vals[16];
#pragma unroll
        for (int r = 0; r < 16; r++) {
            int i = g * 16 + r;
            float acc = ykv[((size_t)h * T + c * CI + i) * D + tid];
            for (int j = 0; j < i; j++) acc += P[i][j] * xls[j][tid];
            vals[r] = acc;
        }
        __syncthreads();
#pragma unroll
        for (int r = 0; r < 16; r++) scr[r * (NN + 1) + tid] = vals[r];
        __syncthreads();
        row_stats16(scr, NN + 1, smu, srs);
        __syncthreads();
#pragma unroll
        for (int r = 0; r < 16; r++) {
            int i = g * 16 + r;
            ykv[((size_t)h * T + c * CI + i) * D + tid] = (vals[r] - smu[r]) * srs[r];
        }
        __syncthreads();
    }
}

// fused: ys = relu(ykv @ encv), xy = xs*ys, yMLP = xy @ dec, x = LN(x + LN(yMLP))
// 16 rows/block, 256 threads.
__global__ void __launch_bounds__(256) k_fuse(const float* __restrict__ ykv,
                                              const float* __restrict__ xs,
                                              const float* __restrict__ encv,
                                              const float* __restrict__ dec,
                                              float* __restrict__ x) {
    int r0 = blockIdx.x * 16, tid = threadIdx.x;
    __shared__ float yls[16][D];          // 16 KB
    __shared__ float xyls[16][NH * NN];   // 64 KB
    __shared__ float smu[16], srs[16];
    for (int h = 0; h < NH; h++) {
        for (int i = tid; i < 16 * D; i += 256) { int ii = i >> 8, kk = i & 255; yls[ii][kk] = ykv[((size_t)h * T + r0 + ii) * D + kk]; }
        __syncthreads();
        const float* ev = encv + (size_t)h * D * NN;
        float acc[16];
#pragma unroll
        for (int r = 0; r < 16; r++) acc[r] = 0.f;
        for (int k = 0; k < D; k++) {
            float w = ev[(size_t)k * NN + tid];
#pragma unroll
            for (int r = 0; r < 16; r++) acc[r] += yls[r][k] * w;
        }
#pragma unroll
        for (int r = 0; r < 16; r++) {
            float ysv = fmaxf(acc[r], 0.f);
            xyls[r][h * NN + tid] = xs[((size_t)h * T + r0 + r) * NN + tid] * ysv;
        }
        __syncthreads();
    }
    float ym[16];
#pragma unroll
    for (int r = 0; r < 16; r++) ym[r] = 0.f;
    for (int k = 0; k < NH * NN; k++) {
        float w = dec[(size_t)k * D + tid];
#pragma unroll
        for (int r = 0; r < 16; r++) ym[r] += xyls[r][k] * w;
    }
    __syncthreads();
#pragma unroll
    for (int r = 0; r < 16; r++) yls[r][tid] = ym[r];
    __syncthreads();
    row_stats16(&yls[0][0], D, smu, srs);
    __syncthreads();
    float z[16];
#pragma unroll
    for (int r = 0; r < 16; r++) z[r] = x[(size_t)(r0 + r) * D + tid] + (ym[r] - smu[r]) * srs[r];
    __syncthreads();
#pragma unroll
    for (int r = 0; r < 16; r++) yls[r][tid] = z[r];
    __syncthreads();
    row_stats16(&yls[0][0], D, smu, srs);
    __syncthreads();
#pragma unroll
    for (int r = 0; r < 16; r++) x[(size_t)(r0 + r) * D + tid] = (z[r] - smu[r]) * srs[r];
}

// logits = x @ lm_head. 32 rows/block, thread = vocab col.
__global__ void __launch_bounds__(256) k_logits(const float* __restrict__ x,
                                                const float* __restrict__ lmh,
                                                float* __restrict__ out) {
    int r0 = blockIdx.x * 32, v = threadIdx.x;
    __shared__ float xls[32][D];
    for (int i = threadIdx.x; i < 32 * D; i += 256) { int ii = i >> 8, kk = i & 255; xls[ii][kk] = x[(size_t)(r0 + ii) * D + kk]; }
    __syncthreads();
    float acc[32];
#pragma unroll
    for (int r = 0; r < 32; r++) acc[r] = 0.f;
    for (int k = 0; k < D; k++) {
        float w = lmh[(size_t)k * VV + v];
#pragma unroll
        for (int r = 0; r < 32; r++) acc[r] += xls[r][k] * w;
    }
#pragma unroll
    for (int r = 0; r < 32; r++) out[(size_t)(r0 + r) * VV + v] = acc[r];
}

// ---------- launch ----------

extern "C" void kernel_launch(void* const* d_in, const int* in_sizes, int n_in,
                              void* d_out, int out_size, void* d_ws, size_t ws_size,
                              hipStream_t stream) {
    const int*   idx   = (const int*)d_in[0];
    const float* embed = (const float*)d_in[1];
    const float* enc   = (const float*)d_in[2];
    const float* encv  = (const float*)d_in[3];
    const float* dec   = (const float*)d_in[4];
    const float* lmh   = (const float*)d_in[5];
    const float* freqs = (const float*)d_in[6];
    float* out = (float*)d_out;

    float* ws   = (float*)d_ws;
    float* x    = ws;                         // T*D          = 1,048,576
    float* rc   = x    + (size_t)T * D;       // T*NN         = 1,048,576
    float* rs   = rc   + (size_t)T * NN;      // T*NN         = 1,048,576
    float* xs   = rs   + (size_t)T * NN;      // NH*T*NN      = 4,194,304
    float* qr   = xs   + (size_t)NH * T * NN; // NH*T*NN      = 4,194,304
    float* ykv  = qr   + (size_t)NH * T * NN; // NH*T*D       = 4,194,304
    float* G    = ykv  + (size_t)NH * T * D;  // NH*NC*NN*D   = 16,777,216
    // total ~127 MB of f32 workspace

    k_embed_ln<<<T, 256, 0, stream>>>(idx, embed, x);
    k_rope<<<T, NN, 0, stream>>>(freqs, rc, rs);

    for (int l = 0; l < NL; l++) {
        k_encode<<<dim3(T / 32, NH), 256, 0, stream>>>(x, enc, rc, rs, xs, qr);
        k_gram  <<<dim3(NN / 32, NC, NH), 256, 0, stream>>>(qr, x, G);
        k_prefix<<<dim3(NN * D / 256, NH), 256, 0, stream>>>(G);
        k_inter <<<dim3(T / 32, NH), 256, 0, stream>>>(qr, G, ykv);
        k_intra <<<dim3(NC, NH), 256, 0, stream>>>(qr, x, ykv);
        k_fuse  <<<T / 16, 256, 0, stream>>>(ykv, xs, encv, dec, x);
    }
    k_logits<<<T / 32, 256, 0, stream>>>(x, lmh, out);
}

// Round 2
// 1636.162 us; speedup vs baseline: 1.2483x; 1.2483x over previous
//
#include <hip/hip_runtime.h>
#include <hip/hip_bf16.h>

#define T   4096
#define D   256
#define NH  4
#define NN  256   // sparse dim
#define NL  4
#define VV  256   // vocab
#define CI  64    // state chunk
#define NC  (T/CI) // 64

__device__ __forceinline__ float4 ld4(const float* p) { return *(const float4*)p; }

// ---------------- prologue ----------------

// x[t] = LN(embed[idx[t]])
__global__ void __launch_bounds__(256) k_embed_ln(const int* __restrict__ idx,
                                                  const float* __restrict__ embed,
                                                  float* __restrict__ x) {
    int t = blockIdx.x, d = threadIdx.x;
    float v = embed[(size_t)idx[t] * D + d];
    __shared__ float red[8];
    float s = v, q = v * v;
#pragma unroll
    for (int m = 1; m < 64; m <<= 1) { s += __shfl_xor(s, m); q += __shfl_xor(q, m); }
    int w = d >> 6;
    if ((d & 63) == 0) { red[w] = s; red[4 + w] = q; }
    __syncthreads();
    s = red[0] + red[1] + red[2] + red[3];
    q = red[4] + red[5] + red[6] + red[7];
    float mu  = s * (1.f / D);
    float var = q * (1.f / D) - mu * mu;
    x[(size_t)t * D + d] = (v - mu) * rsqrtf(fmaxf(var, 0.f) + 1e-5f);
}

// rope tables: phase = frac(t * freqs[n]) * 2pi  (matches ref f32 op order)
__global__ void k_rope(const float* __restrict__ freqs,
                       float* __restrict__ rcos, float* __restrict__ rsin) {
    int t = blockIdx.x, n = threadIdx.x;
    float p  = (float)t * freqs[n];
    float fr = p - floorf(p);
    float ang = fr * 6.283185307179586f;
    rcos[(size_t)t * NN + n] = cosf(ang);
    rsin[(size_t)t * NN + n] = sinf(ang);
}

// ---------------- encode: xs = relu(x@enc), qr = rope(xs) ----------------
// grid (T/32, NH), 256 thr: cg=tid&31 (8 cols each), rg=tid>>5 (4 rows each)
__global__ void __launch_bounds__(256) k_encode(const float* __restrict__ x,
                                                const float* __restrict__ enc,
                                                const float* __restrict__ rcos,
                                                const float* __restrict__ rsin,
                                                float* __restrict__ xs,
                                                float* __restrict__ qr) {
    int h = blockIdx.y, r0 = blockIdx.x * 32;
    int tid = threadIdx.x, cg = tid & 31, rg = tid >> 5;
    int c0 = cg * 8;
    const float* e  = enc + (size_t)h * D * NN;
    const float* ar = x + (size_t)(r0 + rg * 4) * D;
    float acc[4][8];
#pragma unroll
    for (int j = 0; j < 4; j++)
#pragma unroll
        for (int c = 0; c < 8; c++) acc[j][c] = 0.f;
    for (int k4 = 0; k4 < D; k4 += 4) {
        float a_[4][4];
#pragma unroll
        for (int j = 0; j < 4; j++) {
            float4 v = ld4(ar + (size_t)j * D + k4);
            a_[j][0] = v.x; a_[j][1] = v.y; a_[j][2] = v.z; a_[j][3] = v.w;
        }
#pragma unroll
        for (int kk = 0; kk < 4; kk++) {
            float4 b0 = ld4(e + (size_t)(k4 + kk) * NN + c0);
            float4 b1 = ld4(e + (size_t)(k4 + kk) * NN + c0 + 4);
            float bv[8] = {b0.x, b0.y, b0.z, b0.w, b1.x, b1.y, b1.z, b1.w};
#pragma unroll
            for (int j = 0; j < 4; j++)
#pragma unroll
                for (int c = 0; c < 8; c++) acc[j][c] += a_[j][kk] * bv[c];
        }
    }
#pragma unroll
    for (int j = 0; j < 4; j++) {
        int t = r0 + rg * 4 + j;
        float v[8];
#pragma unroll
        for (int c = 0; c < 8; c++) v[c] = fmaxf(acc[j][c], 0.f);
        float4 s0 = {v[0], v[1], v[2], v[3]}, s1 = {v[4], v[5], v[6], v[7]};
        *(float4*)(xs + ((size_t)h * T + t) * NN + c0)     = s0;
        *(float4*)(xs + ((size_t)h * T + t) * NN + c0 + 4) = s1;
        float4 ca = ld4(rcos + (size_t)t * NN + c0), cb = ld4(rcos + (size_t)t * NN + c0 + 4);
        float4 sa = ld4(rsin + (size_t)t * NN + c0), sb = ld4(rsin + (size_t)t * NN + c0 + 4);
        float cs[8] = {ca.x, ca.y, ca.z, ca.w, cb.x, cb.y, cb.z, cb.w};
        float sn[8] = {sa.x, sa.y, sa.z, sa.w, sb.x, sb.y, sb.z, sb.w};
        float qv[8];
#pragma unroll
        for (int p = 0; p < 4; p++) {
            qv[2*p]   = v[2*p]   * cs[2*p]   - v[2*p+1] * sn[2*p];
            qv[2*p+1] = v[2*p+1] * cs[2*p+1] + v[2*p]   * sn[2*p+1];
        }
        float4 q0 = {qv[0], qv[1], qv[2], qv[3]}, q1 = {qv[4], qv[5], qv[6], qv[7]};
        *(float4*)(qr + ((size_t)h * T + t) * NN + c0)     = q0;
        *(float4*)(qr + ((size_t)h * T + t) * NN + c0 + 4) = q1;
    }
}

// ---------------- gram: G[h][c] = QR_c^T @ x_c ----------------
// grid (NN/32, NC, NH); n = n0+rg*4+j, d = cg*8..; K = CI
__global__ void __launch_bounds__(256) k_gram(const float* __restrict__ qr,
                                              const float* __restrict__ x,
                                              float* __restrict__ G) {
    int h = blockIdx.z, c = blockIdx.y, n0 = blockIdx.x * 32;
    int tid = threadIdx.x, cg = tid & 31, rg = tid >> 5;
    int d0 = cg * 8;
    __shared__ float qls[CI][32];   // qls[i][r] = QR[c*CI+i][n0+r]
    for (int i = tid; i < CI * 32; i += 256) {
        int ii = i >> 5, rr = i & 31;
        qls[ii][rr] = qr[((size_t)h * T + c * CI + ii) * NN + n0 + rr];
    }
    __syncthreads();
    const float* xb = x + (size_t)c * CI * D;
    float acc[4][8];
#pragma unroll
    for (int j = 0; j < 4; j++)
#pragma unroll
        for (int cc = 0; cc < 8; cc++) acc[j][cc] = 0.f;
    for (int k4 = 0; k4 < CI; k4 += 4) {
#pragma unroll
        for (int kk = 0; kk < 4; kk++) {
            float4 av = *(const float4*)&qls[k4 + kk][rg * 4];
            float a_[4] = {av.x, av.y, av.z, av.w};
            float4 b0 = ld4(xb + (size_t)(k4 + kk) * D + d0);
            float4 b1 = ld4(xb + (size_t)(k4 + kk) * D + d0 + 4);
            float bv[8] = {b0.x, b0.y, b0.z, b0.w, b1.x, b1.y, b1.z, b1.w};
#pragma unroll
            for (int j = 0; j < 4; j++)
#pragma unroll
                for (int cc = 0; cc < 8; cc++) acc[j][cc] += a_[j] * bv[cc];
        }
    }
#pragma unroll
    for (int j = 0; j < 4; j++) {
        float4 o0 = {acc[j][0], acc[j][1], acc[j][2], acc[j][3]};
        float4 o1 = {acc[j][4], acc[j][5], acc[j][6], acc[j][7]};
        float* gp = G + (((size_t)h * NC + c) * NN + n0 + rg * 4 + j) * D + d0;
        *(float4*)gp = o0; *(float4*)(gp + 4) = o1;
    }
}

// exclusive prefix over chunks, in place
__global__ void k_prefix(float* __restrict__ G) {
    int h = blockIdx.y;
    int pos = blockIdx.x * 256 + threadIdx.x;
    float run = 0.f;
    for (int c = 0; c < NC; c++) {
        float* p = G + ((size_t)h * NC + c) * NN * D + pos;
        float g = *p; *p = run; run += g;
    }
}

// ---------------- attn: ykv = LN(QR@S + strict_tril(QR@QRc^T)@x_c); ys=relu(ykv@encv); xy = xs*ys
// grid (T/32, NH). One block = half a chunk. LDS: xls 64KB + P 8.3KB -> 2 blocks/CU.
__global__ void __launch_bounds__(256) k_attn(const float* __restrict__ qr,
                                              const float* __restrict__ x,
                                              const float* __restrict__ G,
                                              const float* __restrict__ encv,
                                              const float* __restrict__ xs,
                                              float* __restrict__ xy) {
    int h = blockIdx.y, r0 = blockIdx.x * 32;
    int c = r0 / CI, half = (r0 >> 5) & 1;
    int NJ = 32 * (half + 1);
    int tid = threadIdx.x, cg = tid & 31, rg = tid >> 5;
    int c0 = cg * 8;
    __shared__ float xls[CI][D];   // 64 KB (NJ rows used)
    __shared__ float P[32][65];    // 8.3 KB
    // stage x chunk rows (global stores queue; sync below)
    for (int i = tid; i < NJ * D; i += 256) {
        int ii = i >> 8, kk = i & 255;
        xls[ii][kk] = x[(size_t)(c * CI + ii) * D + kk];
    }
    const float* qrow = qr + ((size_t)h * T + r0 + rg * 4) * NN;  // our 4 rows
    const float* qch  = qr + ((size_t)h * T + c * CI) * NN;       // chunk rows
    const float* S    = G + ((size_t)h * NC + c) * NN * D;
    float acc[4][8];
    float pacc[4][2];
#pragma unroll
    for (int j = 0; j < 4; j++) {
#pragma unroll
        for (int cc = 0; cc < 8; cc++) acc[j][cc] = 0.f;
        pacc[j][0] = 0.f; pacc[j][1] = 0.f;
    }
    for (int k4 = 0; k4 < NN; k4 += 4) {
        float a_[4][4];
#pragma unroll
        for (int j = 0; j < 4; j++) {
            float4 v = ld4(qrow + (size_t)j * NN + k4);
            a_[j][0] = v.x; a_[j][1] = v.y; a_[j][2] = v.z; a_[j][3] = v.w;
        }
#pragma unroll
        for (int kk = 0; kk < 4; kk++) {
            float4 b0 = ld4(S + (size_t)(k4 + kk) * D + c0);
            float4 b1 = ld4(S + (size_t)(k4 + kk) * D + c0 + 4);
            float bv[8] = {b0.x, b0.y, b0.z, b0.w, b1.x, b1.y, b1.z, b1.w};
#pragma unroll
            for (int j = 0; j < 4; j++)
#pragma unroll
                for (int cc = 0; cc < 8; cc++) acc[j][cc] += a_[j][kk] * bv[cc];
        }
        // P part: P[i][jj] = QR_i . QR_jj  (jj = jt*32+cg)
        for (int jt = 0; jt <= half; jt++) {
            float4 pb = ld4(qch + (size_t)(jt * 32 + cg) * NN + k4);
            float pb_[4] = {pb.x, pb.y, pb.z, pb.w};
#pragma unroll
            for (int kk = 0; kk < 4; kk++)
#pragma unroll
                for (int j = 0; j < 4; j++) pacc[j][jt] += a_[j][kk] * pb_[kk];
        }
    }
#pragma unroll
    for (int j = 0; j < 4; j++) {
        P[rg * 4 + j][cg] = pacc[j][0];
        if (half) P[rg * 4 + j][32 + cg] = pacc[j][1];
    }
    __syncthreads();
    // intra apply: acc[j] += sum_{jj < ic} P[row][jj] * x_c[jj]
#pragma unroll
    for (int j = 0; j < 4; j++) {
        int ic = half * 32 + rg * 4 + j;   // strict upper bound (chunk-local)
        for (int jj = 0; jj < ic; jj++) {
            float p = P[rg * 4 + j][jj];
            float4 xv0 = *(const float4*)&xls[jj][c0];
            float4 xv1 = *(const float4*)&xls[jj][c0 + 4];
            acc[j][0] += p * xv0.x; acc[j][1] += p * xv0.y;
            acc[j][2] += p * xv0.z; acc[j][3] += p * xv0.w;
            acc[j][4] += p * xv1.x; acc[j][5] += p * xv1.y;
            acc[j][6] += p * xv1.z; acc[j][7] += p * xv1.w;
        }
    }
    // LN per row (32 cg-lanes hold the 256 cols)
    float nrm[4][8];
#pragma unroll
    for (int j = 0; j < 4; j++) {
        float s = 0.f, q = 0.f;
#pragma unroll
        for (int cc = 0; cc < 8; cc++) { s += acc[j][cc]; q += acc[j][cc] * acc[j][cc]; }
#pragma unroll
        for (int m = 1; m < 32; m <<= 1) { s += __shfl_xor(s, m); q += __shfl_xor(q, m); }
        float mu   = s * (1.f / D);
        float rstd = rsqrtf(fmaxf(q * (1.f / D) - mu * mu, 0.f) + 1e-5f);
#pragma unroll
        for (int cc = 0; cc < 8; cc++) nrm[j][cc] = (acc[j][cc] - mu) * rstd;
    }
    __syncthreads();   // xls reads done; safe to overwrite
#pragma unroll
    for (int j = 0; j < 4; j++) {
        float4 n0v = {nrm[j][0], nrm[j][1], nrm[j][2], nrm[j][3]};
        float4 n1v = {nrm[j][4], nrm[j][5], nrm[j][6], nrm[j][7]};
        *(float4*)&xls[rg * 4 + j][c0]     = n0v;
        *(float4*)&xls[rg * 4 + j][c0 + 4] = n1v;
    }
    __syncthreads();
    // ys GEMM: relu(ykv_norm @ encv[h]); gate by xs; store xy[t][h*NN+n]
    const float* ev = encv + (size_t)h * D * NN;
    float acc2[4][8];
#pragma unroll
    for (int j = 0; j < 4; j++)
#pragma unroll
        for (int cc = 0; cc < 8; cc++) acc2[j][cc] = 0.f;
    for (int k4 = 0; k4 < D; k4 += 4) {
        float a_[4][4];
#pragma unroll
        for (int j = 0; j < 4; j++) {
            float4 v = *(const float4*)&xls[rg * 4 + j][k4];
            a_[j][0] = v.x; a_[j][1] = v.y; a_[j][2] = v.z; a_[j][3] = v.w;
        }
#pragma unroll
        for (int kk = 0; kk < 4; kk++) {
            float4 b0 = ld4(ev + (size_t)(k4 + kk) * NN + c0);
            float4 b1 = ld4(ev + (size_t)(k4 + kk) * NN + c0 + 4);
            float bv[8] = {b0.x, b0.y, b0.z, b0.w, b1.x, b1.y, b1.z, b1.w};
#pragma unroll
            for (int j = 0; j < 4; j++)
#pragma unroll
                for (int cc = 0; cc < 8; cc++) acc2[j][cc] += a_[j][kk] * bv[cc];
        }
    }
#pragma unroll
    for (int j = 0; j < 4; j++) {
        int t = r0 + rg * 4 + j;
        float4 g0 = ld4(xs + ((size_t)h * T + t) * NN + c0);
        float4 g1 = ld4(xs + ((size_t)h * T + t) * NN + c0 + 4);
        float gv[8] = {g0.x, g0.y, g0.z, g0.w, g1.x, g1.y, g1.z, g1.w};
        float o[8];
#pragma unroll
        for (int cc = 0; cc < 8; cc++) o[cc] = fmaxf(acc2[j][cc], 0.f) * gv[cc];
        float4 o0 = {o[0], o[1], o[2], o[3]}, o1 = {o[4], o[5], o[6], o[7]};
        float* op = xy + (size_t)t * (NH * NN) + h * NN + c0;
        *(float4*)op = o0; *(float4*)(op + 4) = o1;
    }
}

// ---------------- mlp: yMLP = xy @ dec; x = LN(x + LN(yMLP)) ----------------
// grid T/8, 256 thr: cg64=tid&63 (4 cols), wave rg=tid>>6 (2 rows). K=1024. No LDS.
__global__ void __launch_bounds__(256) k_mlp(const float* __restrict__ xy,
                                             const float* __restrict__ dec,
                                             float* __restrict__ x) {
    int r0 = blockIdx.x * 8;
    int tid = threadIdx.x, cg = tid & 63, rg = tid >> 6;
    int c0 = cg * 4;
    const float* ar = xy + (size_t)(r0 + rg * 2) * (NH * NN);
    float acc[2][4];
#pragma unroll
    for (int j = 0; j < 2; j++)
#pragma unroll
        for (int cc = 0; cc < 4; cc++) acc[j][cc] = 0.f;
    for (int k4 = 0; k4 < NH * NN; k4 += 4) {
        float a_[2][4];
#pragma unroll
        for (int j = 0; j < 2; j++) {
            float4 v = ld4(ar + (size_t)j * (NH * NN) + k4);
            a_[j][0] = v.x; a_[j][1] = v.y; a_[j][2] = v.z; a_[j][3] = v.w;
        }
#pragma unroll
        for (int kk = 0; kk < 4; kk++) {
            float4 b = ld4(dec + (size_t)(k4 + kk) * D + c0);
            float bv[4] = {b.x, b.y, b.z, b.w};
#pragma unroll
            for (int j = 0; j < 2; j++)
#pragma unroll
                for (int cc = 0; cc < 4; cc++) acc[j][cc] += a_[j][kk] * bv[cc];
        }
    }
#pragma unroll
    for (int j = 0; j < 2; j++) {
        int t = r0 + rg * 2 + j;
        // LN(yMLP)
        float s = 0.f, q = 0.f;
#pragma unroll
        for (int cc = 0; cc < 4; cc++) { s += acc[j][cc]; q += acc[j][cc] * acc[j][cc]; }
#pragma unroll
        for (int m = 1; m < 64; m <<= 1) { s += __shfl_xor(s, m); q += __shfl_xor(q, m); }
        float mu   = s * (1.f / D);
        float rstd = rsqrtf(fmaxf(q * (1.f / D) - mu * mu, 0.f) + 1e-5f);
        float4 xo = ld4(x + (size_t)t * D + c0);
        float xv[4] = {xo.x, xo.y, xo.z, xo.w};
        float z[4];
#pragma unroll
        for (int cc = 0; cc < 4; cc++) z[cc] = xv[cc] + (acc[j][cc] - mu) * rstd;
        // LN(x + .)
        float s2 = 0.f, q2 = 0.f;
#pragma unroll
        for (int cc = 0; cc < 4; cc++) { s2 += z[cc]; q2 += z[cc] * z[cc]; }
#pragma unroll
        for (int m = 1; m < 64; m <<= 1) { s2 += __shfl_xor(s2, m); q2 += __shfl_xor(q2, m); }
        float mu2   = s2 * (1.f / D);
        float rstd2 = rsqrtf(fmaxf(q2 * (1.f / D) - mu2 * mu2, 0.f) + 1e-5f);
        float4 o = {(z[0] - mu2) * rstd2, (z[1] - mu2) * rstd2,
                    (z[2] - mu2) * rstd2, (z[3] - mu2) * rstd2};
        *(float4*)(x + (size_t)t * D + c0) = o;
    }
}

// ---------------- logits: out = x @ lm_head ----------------
// grid T/8, 256 thr: 2 rows x 4 cols per thread
__global__ void __launch_bounds__(256) k_logits(const float* __restrict__ x,
                                                const float* __restrict__ lmh,
                                                float* __restrict__ out) {
    int r0 = blockIdx.x * 8;
    int tid = threadIdx.x, cg = tid & 63, rg = tid >> 6;
    int c0 = cg * 4;
    const float* ar = x + (size_t)(r0 + rg * 2) * D;
    float acc[2][4];
#pragma unroll
    for (int j = 0; j < 2; j++)
#pragma unroll
        for (int cc = 0; cc < 4; cc++) acc[j][cc] = 0.f;
    for (int k4 = 0; k4 < D; k4 += 4) {
        float a_[2][4];
#pragma unroll
        for (int j = 0; j < 2; j++) {
            float4 v = ld4(ar + (size_t)j * D + k4);
            a_[j][0] = v.x; a_[j][1] = v.y; a_[j][2] = v.z; a_[j][3] = v.w;
        }
#pragma unroll
        for (int kk = 0; kk < 4; kk++) {
            float4 b = ld4(lmh + (size_t)(k4 + kk) * VV + c0);
            float bv[4] = {b.x, b.y, b.z, b.w};
#pragma unroll
            for (int j = 0; j < 2; j++)
#pragma unroll
                for (int cc = 0; cc < 4; cc++) acc[j][cc] += a_[j][kk] * bv[cc];
        }
    }
#pragma unroll
    for (int j = 0; j < 2; j++) {
        float4 o = {acc[j][0], acc[j][1], acc[j][2], acc[j][3]};
        *(float4*)(out + (size_t)(r0 + rg * 2 + j) * VV + c0) = o;
    }
}

// ---------------- launch ----------------

extern "C" void kernel_launch(void* const* d_in, const int* in_sizes, int n_in,
                              void* d_out, int out_size, void* d_ws, size_t ws_size,
                              hipStream_t stream) {
    const int*   idx   = (const int*)d_in[0];
    const float* embed = (const float*)d_in[1];
    const float* enc   = (const float*)d_in[2];
    const float* encv  = (const float*)d_in[3];
    const float* dec   = (const float*)d_in[4];
    const float* lmh   = (const float*)d_in[5];
    const float* freqs = (const float*)d_in[6];
    float* out = (float*)d_out;

    float* ws   = (float*)d_ws;
    float* x    = ws;                          // T*D
    float* rc   = x    + (size_t)T * D;        // T*NN
    float* rs   = rc   + (size_t)T * NN;       // T*NN
    float* xs   = rs   + (size_t)T * NN;       // NH*T*NN
    float* qr   = xs   + (size_t)NH * T * NN;  // NH*T*NN
    float* xy   = qr   + (size_t)NH * T * NN;  // T*NH*NN
    float* G    = xy   + (size_t)T * NH * NN;  // NH*NC*NN*D

    k_embed_ln<<<T, 256, 0, stream>>>(idx, embed, x);
    k_rope<<<T, NN, 0, stream>>>(freqs, rc, rs);

    for (int l = 0; l < NL; l++) {
        k_encode<<<dim3(T / 32, NH), 256, 0, stream>>>(x, enc, rc, rs, xs, qr);
        k_gram  <<<dim3(NN / 32, NC, NH), 256, 0, stream>>>(qr, x, G);
        k_prefix<<<dim3(NN * D / 256, NH), 256, 0, stream>>>(G);
        k_attn  <<<dim3(T / 32, NH), 256, 0, stream>>>(qr, x, G, encv, xs, xy);
        k_mlp   <<<T / 8, 256, 0, stream>>>(xy, dec, x);
    }
    k_logits<<<T / 8, 256, 0, stream>>>(x, lmh, out);
}

// Round 5
// 611.205 us; speedup vs baseline: 3.3415x; 2.6769x over previous
//
#include <hip/hip_runtime.h>
#include <hip/hip_bf16.h>

#define T   4096
#define D   256
#define NH  4
#define NN  256
#define NL  4
#define VV  256
#define CI  64
#define NC  (T/CI)

typedef short bf16x4 __attribute__((ext_vector_type(4)));
typedef short bf16x8 __attribute__((ext_vector_type(8)));
typedef float f32x4  __attribute__((ext_vector_type(4)));

__device__ __forceinline__ short f2bf(float f) {
    union { float f; unsigned u; } v; v.f = f;
    unsigned r = v.u + 0x7fffu + ((v.u >> 16) & 1u);
    return (short)(r >> 16);
}
__device__ __forceinline__ float bf2f(short s) {
    union { unsigned u; float f; } v; v.u = ((unsigned)(unsigned short)s) << 16;
    return v.f;
}
__device__ __forceinline__ f32x4 mfma16(bf16x8 a, bf16x8 b, f32x4 c) {
    return __builtin_amdgcn_mfma_f32_16x16x32_bf16(a, b, c, 0, 0, 0);
}

// ---------- weight prep: dst[b][c][r] = bf16(src[b][r][c]) ----------
__global__ void __launch_bounds__(256) k_wtr(const float* __restrict__ src,
                                             short* __restrict__ dst, int R, int C) {
    int b = blockIdx.z, r0 = blockIdx.x * 16, c0 = blockIdx.y * 16;
    int i = threadIdx.x >> 4, j = threadIdx.x & 15;
    __shared__ float tile[16][17];
    tile[i][j] = src[((size_t)b * R + r0 + i) * C + c0 + j];
    __syncthreads();
    dst[((size_t)b * C + c0 + i) * R + r0 + j] = f2bf(tile[j][i]);
}

// ---------- rope tables (row-major [t][n]) ----------
__global__ void k_rope(const float* __restrict__ freqs,
                       float* __restrict__ rcos, float* __restrict__ rsin) {
    int t = blockIdx.x, n = threadIdx.x;
    float p = (float)t * freqs[n];
    float fr = p - floorf(p);
    float ang = fr * 6.283185307179586f;
    rcos[(size_t)t * NN + n] = cosf(ang);
    rsin[(size_t)t * NN + n] = sinf(ang);
}

// ---------- embed + LN -> xT (bf16 [D][T]) ----------
__global__ void __launch_bounds__(256) k_embed(const int* __restrict__ idx,
                                               const float* __restrict__ embed,
                                               short* __restrict__ xT) {
    int t0 = blockIdx.x * 32, tid = threadIdx.x;
    __shared__ float ld[32][257];
    __shared__ int ridx[32];
    __shared__ float mu_s[32], rs_s[32];
    if (tid < 32) ridx[tid] = idx[t0 + tid];
    __syncthreads();
    for (int k = 0; k < 32; k++) ld[k][tid] = embed[(size_t)ridx[k] * D + tid];
    __syncthreads();
    int r = tid >> 3, l8 = tid & 7;
    float s = 0.f, q = 0.f;
    for (int d = l8; d < D; d += 8) { float v = ld[r][d]; s += v; q += v * v; }
#pragma unroll
    for (int m = 1; m < 8; m <<= 1) { s += __shfl_xor(s, m); q += __shfl_xor(q, m); }
    if (l8 == 0) {
        float mu = s * (1.f / D);
        float var = q * (1.f / D) - mu * mu;
        mu_s[r] = mu; rs_s[r] = rsqrtf(fmaxf(var, 0.f) + 1e-5f);
    }
    __syncthreads();
    short vals[32];
#pragma unroll
    for (int rr = 0; rr < 32; rr++) vals[rr] = f2bf((ld[rr][tid] - mu_s[rr]) * rs_s[rr]);
    bf16x8* p = (bf16x8*)(xT + (size_t)tid * T + t0);
#pragma unroll
    for (int u = 0; u < 4; u++) p[u] = *(bf16x8*)&vals[u * 8];
}

// ---------- generic bf16 transpose: src[z][R][C] -> dst[z][C][R] ----------
__global__ void __launch_bounds__(256) k_tr(const short* __restrict__ src,
                                            short* __restrict__ dst, int R, int C) {
    int z = blockIdx.z;
    int c0 = blockIdx.x * 64, r0 = blockIdx.y * 64;
    int tid = threadIdx.x;
    __shared__ short ld[64][72];
    const short* s = src + (size_t)z * R * C;
    short* d = dst + (size_t)z * R * C;
    {
        int i = tid >> 2, c4 = (tid & 3) * 16;
        const bf16x8* p = (const bf16x8*)(s + (size_t)(r0 + i) * C + c0 + c4);
        bf16x8 v0 = p[0], v1 = p[1];
        int sw = (i & 7) << 3;
        *(bf16x8*)&ld[i][c4 ^ sw] = v0;
        *(bf16x8*)&ld[i][(c4 + 8) ^ sw] = v1;
    }
    __syncthreads();
    {
        int j = tid >> 2, r4 = (tid & 3) * 16;
        short vals[16];
#pragma unroll
        for (int m = 0; m < 16; m++) vals[m] = ld[r4 + m][j ^ ((m & 7) << 3)];
        bf16x8* q = (bf16x8*)(d + (size_t)(c0 + j) * R + r0 + r4);
        q[0] = *(bf16x8*)&vals[0];
        q[1] = *(bf16x8*)&vals[8];
    }
}

// ---------- encode (swapped): C[n][t] = encT @ x^T; xs=relu, qr=rope ----------
__global__ void __launch_bounds__(256) k_encode(const short* __restrict__ x_bf,
                                                const short* __restrict__ encT,
                                                const float* __restrict__ rc,
                                                const float* __restrict__ rs,
                                                short* __restrict__ xs,
                                                short* __restrict__ qr) {
    int h = blockIdx.y, t0 = blockIdx.x * 32;
    int tid = threadIdx.x, w = tid >> 6, l = tid & 63;
    int l15 = l & 15, lk = (l >> 4) * 8, lr4 = (l >> 4) * 4;
    int nstrip = w * 64;
    const short* ebase = encT + ((size_t)h * NN + nstrip + l15) * D + lk;
    const short* xbase = x_bf + (size_t)(t0 + l15) * D + lk;
    f32x4 acc[4][2];
#pragma unroll
    for (int rt = 0; rt < 4; rt++)
#pragma unroll
        for (int tt = 0; tt < 2; tt++) acc[rt][tt] = (f32x4){0.f, 0.f, 0.f, 0.f};
    for (int k0 = 0; k0 < D; k0 += 32) {
        bf16x8 a[4], b[2];
#pragma unroll
        for (int rt = 0; rt < 4; rt++) a[rt] = *(const bf16x8*)(ebase + rt * 16 * D + k0);
#pragma unroll
        for (int tt = 0; tt < 2; tt++) b[tt] = *(const bf16x8*)(xbase + tt * 16 * D + k0);
#pragma unroll
        for (int rt = 0; rt < 4; rt++)
#pragma unroll
            for (int tt = 0; tt < 2; tt++) acc[rt][tt] = mfma16(a[rt], b[tt], acc[rt][tt]);
    }
#pragma unroll
    for (int rt = 0; rt < 4; rt++)
#pragma unroll
        for (int tt = 0; tt < 2; tt++) {
            int t = t0 + tt * 16 + l15;
            int n0 = nstrip + rt * 16 + lr4;
            float v[4], rot[4];
#pragma unroll
            for (int r = 0; r < 4; r++) v[r] = fmaxf(acc[rt][tt][r], 0.f);
            rot[0] = -v[1]; rot[1] = v[0]; rot[2] = -v[3]; rot[3] = v[2];
            bf16x4 xsv;
#pragma unroll
            for (int r = 0; r < 4; r++) xsv[r] = f2bf(v[r]);
            *(bf16x4*)(xs + ((size_t)h * T + t) * NN + n0) = xsv;
            float4 cv = *(const float4*)(rc + (size_t)t * NN + n0);
            float4 sv = *(const float4*)(rs + (size_t)t * NN + n0);
            float cc[4] = {cv.x, cv.y, cv.z, cv.w}, ss[4] = {sv.x, sv.y, sv.z, sv.w};
            bf16x4 qv;
#pragma unroll
            for (int r = 0; r < 4; r++) qv[r] = f2bf(v[r] * cc[r] + rot[r] * ss[r]);
            *(bf16x4*)(qr + ((size_t)h * T + t) * NN + n0) = qv;
        }
}

// ---------- gram: C[n][d] = qrT_chunk @ xT_chunk^T -> Graw[h][c][d][n] bf16 ----------
__global__ void __launch_bounds__(256) k_gram(const short* __restrict__ qrT,
                                              const short* __restrict__ xT,
                                              short* __restrict__ Graw) {
    int h = blockIdx.z, c = blockIdx.y, n0 = blockIdx.x * 64;
    int tid = threadIdx.x, w = tid >> 6, l = tid & 63;
    int l15 = l & 15, lk = (l >> 4) * 8, lr4 = (l >> 4) * 4;
    const short* abase = qrT + ((size_t)h * NN + n0 + w * 16 + l15) * T + c * CI + lk;
    const short* bbase = xT + (size_t)l15 * T + c * CI + lk;
    f32x4 acc[16];
#pragma unroll
    for (int dt = 0; dt < 16; dt++) acc[dt] = (f32x4){0.f, 0.f, 0.f, 0.f};
#pragma unroll
    for (int ki = 0; ki < 2; ki++) {
        int k0 = ki * 32;
        bf16x8 a = *(const bf16x8*)(abase + k0);
#pragma unroll
        for (int dt = 0; dt < 16; dt++) {
            bf16x8 b = *(const bf16x8*)(bbase + (size_t)dt * 16 * T + k0);
            acc[dt] = mfma16(a, b, acc[dt]);
        }
    }
#pragma unroll
    for (int dt = 0; dt < 16; dt++) {
        int d = dt * 16 + l15;
        bf16x4 o;
#pragma unroll
        for (int r = 0; r < 4; r++) o[r] = f2bf(acc[dt][r]);
        *(bf16x4*)(Graw + (((size_t)h * NC + c) * D + d) * NN + n0 + w * 16 + lr4) = o;
    }
}

// ---------- exclusive prefix over chunks: Sp[c] = sum_{c'<c} Graw[c'] ----------
__global__ void __launch_bounds__(256) k_prefix(const short* __restrict__ Graw,
                                                short* __restrict__ Sp) {
    int pos = (blockIdx.x * 256 + threadIdx.x) * 4;
    int h = pos >> 16;
    int rem = pos & 65535;
    float run[4] = {0.f, 0.f, 0.f, 0.f};
    for (int c = 0; c < NC; c++) {
        size_t ix = ((size_t)h * NC + c) * 65536 + rem;
        bf16x4 g = *(const bf16x4*)(Graw + ix);
        bf16x4 o;
#pragma unroll
        for (int e = 0; e < 4; e++) { o[e] = f2bf(run[e]); run[e] += bf2f(g[e]); }
        *(bf16x4*)(Sp + ix) = o;
    }
}

// ---------- attn: yKV = LN(QR@S + tril_strict(QR@QRc^T)@x_c); ys=relu(yKV@encv); xy = xs*ys ----------
__global__ void __launch_bounds__(256) k_attn(const short* __restrict__ qr,
                                              const short* __restrict__ xT,
                                              const short* __restrict__ Sp,
                                              const short* __restrict__ encvT,
                                              const short* __restrict__ xs,
                                              short* __restrict__ xy) {
    int h = blockIdx.y, t0 = blockIdx.x * 32;
    int c = t0 >> 6, cl0 = t0 & 63;
    int tid = threadIdx.x, w = tid >> 6, l = tid & 63;
    int l15 = l & 15, lk = (l >> 4) * 8, lr4 = (l >> 4) * 4;
    int ts = w & 1, dh = w >> 1;
    __shared__ short P_lds[32][72];
    __shared__ short ynorm[32 * 256];   // stride 256 shorts = 128 dwords (0 mod 32) so the
                                        // XOR swizzle alone sets bank rotation (2-way, free)
    __shared__ float lnb[2][32][2];
    int njt = cl0 ? 4 : 2;
    const short* qa  = qr + ((size_t)h * T + t0 + ts * 16 + l15) * NN + lk;
    const short* qpb = qr + ((size_t)h * T + c * CI + l15) * NN + lk;
    const short* sb  = Sp + (((size_t)h * NC + c) * D + dh * 128 + l15) * NN + lk;
    f32x4 akv[8], ap[4];
#pragma unroll
    for (int dt = 0; dt < 8; dt++) akv[dt] = (f32x4){0.f, 0.f, 0.f, 0.f};
#pragma unroll
    for (int jt = 0; jt < 4; jt++) ap[jt] = (f32x4){0.f, 0.f, 0.f, 0.f};
    for (int k0 = 0; k0 < NN; k0 += 32) {
        bf16x8 a = *(const bf16x8*)(qa + k0);
#pragma unroll
        for (int dt = 0; dt < 8; dt++) {
            bf16x8 bs = *(const bf16x8*)(sb + (size_t)dt * 16 * NN + k0);
            akv[dt] = mfma16(a, bs, akv[dt]);
        }
        if (dh == 0) {
#pragma unroll
            for (int jt = 0; jt < 4; jt++) {
                if (jt < njt) {   // static index into ap[] (rule #20: no runtime-bound indexing)
                    bf16x8 bp = *(const bf16x8*)(qpb + (size_t)jt * 16 * NN + k0);
                    ap[jt] = mfma16(a, bp, ap[jt]);
                }
            }
        }
    }
    if (dh == 0) {
#pragma unroll
        for (int jt = 0; jt < 4; jt++) {
            if (jt < njt) {
#pragma unroll
                for (int r = 0; r < 4; r++) {
                    int il = ts * 16 + lr4 + r;
                    int jcl = jt * 16 + l15;
                    float pv = (jcl < cl0 + il) ? ap[jt][r] : 0.f;
                    P_lds[il][jcl] = f2bf(pv);
                }
            }
        }
    }
    __syncthreads();
    int nks = cl0 ? 2 : 1;
    for (int ki = 0; ki < nks; ki++) {
        int k0 = ki * 32;
        bf16x8 a = *(const bf16x8*)(&P_lds[ts * 16 + l15][k0 + lk]);
#pragma unroll
        for (int dt = 0; dt < 8; dt++) {
            bf16x8 b = *(const bf16x8*)(xT + (size_t)(dh * 128 + dt * 16 + l15) * T + c * CI + k0 + lk);
            akv[dt] = mfma16(a, b, akv[dt]);
        }
    }
    // LayerNorm over d
    float s[4], q[4], mu[4], rstd[4];
#pragma unroll
    for (int r = 0; r < 4; r++) { s[r] = 0.f; q[r] = 0.f; }
#pragma unroll
    for (int dt = 0; dt < 8; dt++)
#pragma unroll
        for (int r = 0; r < 4; r++) { float v = akv[dt][r]; s[r] += v; q[r] += v * v; }
#pragma unroll
    for (int m = 1; m < 16; m <<= 1)
#pragma unroll
        for (int r = 0; r < 4; r++) { s[r] += __shfl_xor(s[r], m); q[r] += __shfl_xor(q[r], m); }
    if (l15 == 0) {
#pragma unroll
        for (int r = 0; r < 4; r++) {
            int rl = ts * 16 + lr4 + r;
            lnb[dh][rl][0] = s[r]; lnb[dh][rl][1] = q[r];
        }
    }
    __syncthreads();
#pragma unroll
    for (int r = 0; r < 4; r++) {
        int rl = ts * 16 + lr4 + r;
        float st = lnb[0][rl][0] + lnb[1][rl][0];
        float qt = lnb[0][rl][1] + lnb[1][rl][1];
        float m_ = st * (1.f / D);
        float var = qt * (1.f / D) - m_ * m_;
        mu[r] = m_; rstd[r] = rsqrtf(fmaxf(var, 0.f) + 1e-5f);
    }
#pragma unroll
    for (int dt = 0; dt < 8; dt++)
#pragma unroll
        for (int r = 0; r < 4; r++) {
            int row = ts * 16 + lr4 + r;
            int dcol = dh * 128 + dt * 16 + l15;
            ynorm[row * 256 + (dcol ^ ((row & 7) << 3))] = f2bf((akv[dt][r] - mu[r]) * rstd[r]);
        }
    __syncthreads();
    // ys (swapped): C[n][t] = encvT @ ynorm^T
    int nstrip = w * 64;
    f32x4 a2[4][2];
#pragma unroll
    for (int nt = 0; nt < 4; nt++)
#pragma unroll
        for (int tt = 0; tt < 2; tt++) a2[nt][tt] = (f32x4){0.f, 0.f, 0.f, 0.f};
    const short* ev = encvT + ((size_t)h * NN + nstrip + l15) * D + lk;
    for (int k0 = 0; k0 < D; k0 += 32) {
        bf16x8 av[4], bv[2];
#pragma unroll
        for (int nt = 0; nt < 4; nt++) av[nt] = *(const bf16x8*)(ev + nt * 16 * D + k0);
#pragma unroll
        for (int tt = 0; tt < 2; tt++) {
            int row = tt * 16 + l15;
            int col = k0 + lk;
            bv[tt] = *(const bf16x8*)&ynorm[row * 256 + (col ^ ((row & 7) << 3))];
        }
#pragma unroll
        for (int nt = 0; nt < 4; nt++)
#pragma unroll
            for (int tt = 0; tt < 2; tt++) a2[nt][tt] = mfma16(av[nt], bv[tt], a2[nt][tt]);
    }
#pragma unroll
    for (int nt = 0; nt < 4; nt++)
#pragma unroll
        for (int tt = 0; tt < 2; tt++) {
            int n0 = nstrip + nt * 16 + lr4;
            int t = t0 + tt * 16 + l15;
            bf16x4 g = *(const bf16x4*)(xs + ((size_t)h * T + t) * NN + n0);
            bf16x4 o;
#pragma unroll
            for (int r = 0; r < 4; r++) o[r] = f2bf(fmaxf(a2[nt][tt][r], 0.f) * bf2f(g[r]));
            *(bf16x4*)(xy + (size_t)t * (NH * NN) + h * NN + n0) = o;
        }
}

// ---------- mlp: yMLP = xy @ dec; x = LN(x + LN(yMLP)); writes xT in-place ----------
__global__ void __launch_bounds__(256) k_mlp(const short* __restrict__ xy,
                                             const short* __restrict__ decT,
                                             short* __restrict__ xT) {
    int t0 = blockIdx.x * 16;
    int tid = threadIdx.x, w = tid >> 6, l = tid & 63;
    int l15 = l & 15, lk = (l >> 4) * 8, lr4 = (l >> 4) * 4;
    __shared__ float lnb[4][16][2];
    const short* abase = xy + (size_t)(t0 + l15) * (NH * NN) + lk;
    const short* bbase = decT + (size_t)(w * 64 + l15) * (NH * NN) + lk;
    f32x4 acc[4];
#pragma unroll
    for (int dt = 0; dt < 4; dt++) acc[dt] = (f32x4){0.f, 0.f, 0.f, 0.f};
    for (int k0 = 0; k0 < NH * NN; k0 += 32) {
        bf16x8 a = *(const bf16x8*)(abase + k0);
#pragma unroll
        for (int dt = 0; dt < 4; dt++) {
            bf16x8 b = *(const bf16x8*)(bbase + (size_t)dt * 16 * (NH * NN) + k0);
            acc[dt] = mfma16(a, b, acc[dt]);
        }
    }
    float s[4], q[4];
#pragma unroll
    for (int r = 0; r < 4; r++) { s[r] = 0.f; q[r] = 0.f; }
#pragma unroll
    for (int dt = 0; dt < 4; dt++)
#pragma unroll
        for (int r = 0; r < 4; r++) { float v = acc[dt][r]; s[r] += v; q[r] += v * v; }
#pragma unroll
    for (int m = 1; m < 16; m <<= 1)
#pragma unroll
        for (int r = 0; r < 4; r++) { s[r] += __shfl_xor(s[r], m); q[r] += __shfl_xor(q[r], m); }
    if (l15 == 0)
#pragma unroll
        for (int r = 0; r < 4; r++) { lnb[w][lr4 + r][0] = s[r]; lnb[w][lr4 + r][1] = q[r]; }
    __syncthreads();
    float mu1[4], rstd1[4];
#pragma unroll
    for (int r = 0; r < 4; r++) {
        float st = 0.f, qt = 0.f;
#pragma unroll
        for (int ww = 0; ww < 4; ww++) { st += lnb[ww][lr4 + r][0]; qt += lnb[ww][lr4 + r][1]; }
        float m_ = st * (1.f / D);
        float var = qt * (1.f / D) - m_ * m_;
        mu1[r] = m_; rstd1[r] = rsqrtf(fmaxf(var, 0.f) + 1e-5f);
    }
    float z[4][4];
#pragma unroll
    for (int dt = 0; dt < 4; dt++) {
        bf16x4 xo = *(const bf16x4*)(xT + (size_t)(w * 64 + dt * 16 + l15) * T + t0 + lr4);
#pragma unroll
        for (int r = 0; r < 4; r++)
            z[dt][r] = bf2f(xo[r]) + (acc[dt][r] - mu1[r]) * rstd1[r];
    }
#pragma unroll
    for (int r = 0; r < 4; r++) { s[r] = 0.f; q[r] = 0.f; }
#pragma unroll
    for (int dt = 0; dt < 4; dt++)
#pragma unroll
        for (int r = 0; r < 4; r++) { float v = z[dt][r]; s[r] += v; q[r] += v * v; }
#pragma unroll
    for (int m = 1; m < 16; m <<= 1)
#pragma unroll
        for (int r = 0; r < 4; r++) { s[r] += __shfl_xor(s[r], m); q[r] += __shfl_xor(q[r], m); }
    __syncthreads();
    if (l15 == 0)
#pragma unroll
        for (int r = 0; r < 4; r++) { lnb[w][lr4 + r][0] = s[r]; lnb[w][lr4 + r][1] = q[r]; }
    __syncthreads();
#pragma unroll
    for (int r = 0; r < 4; r++) {
        float st = 0.f, qt = 0.f;
#pragma unroll
        for (int ww = 0; ww < 4; ww++) { st += lnb[ww][lr4 + r][0]; qt += lnb[ww][lr4 + r][1]; }
        float m_ = st * (1.f / D);
        float var = qt * (1.f / D) - m_ * m_;
        mu1[r] = m_; rstd1[r] = rsqrtf(fmaxf(var, 0.f) + 1e-5f);
    }
#pragma unroll
    for (int dt = 0; dt < 4; dt++) {
        bf16x4 o;
#pragma unroll
        for (int r = 0; r < 4; r++) o[r] = f2bf((z[dt][r] - mu1[r]) * rstd1[r]);
        *(bf16x4*)(xT + (size_t)(w * 64 + dt * 16 + l15) * T + t0 + lr4) = o;
    }
}

// ---------- logits (swapped): C[v][t] = lmhT @ x^T -> out[t][v] f32 ----------
__global__ void __launch_bounds__(256) k_logits(const short* __restrict__ x_bf,
                                                const short* __restrict__ lmhT,
                                                float* __restrict__ out) {
    int t0 = blockIdx.x * 16;
    int tid = threadIdx.x, w = tid >> 6, l = tid & 63;
    int l15 = l & 15, lk = (l >> 4) * 8, lr4 = (l >> 4) * 4;
    const short* ab = lmhT + (size_t)(w * 64 + l15) * D + lk;
    const short* bb = x_bf + (size_t)(t0 + l15) * D + lk;
    f32x4 acc[4];
#pragma unroll
    for (int vt = 0; vt < 4; vt++) acc[vt] = (f32x4){0.f, 0.f, 0.f, 0.f};
    for (int k0 = 0; k0 < D; k0 += 32) {
        bf16x8 b = *(const bf16x8*)(bb + k0);
#pragma unroll
        for (int vt = 0; vt < 4; vt++) {
            bf16x8 a = *(const bf16x8*)(ab + (size_t)vt * 16 * D + k0);
            acc[vt] = mfma16(a, b, acc[vt]);
        }
    }
#pragma unroll
    for (int vt = 0; vt < 4; vt++) {
        int t = t0 + l15;
        int v0 = w * 64 + vt * 16 + lr4;
        *(f32x4*)(out + (size_t)t * VV + v0) = acc[vt];
    }
}

// ---------- launch ----------
extern "C" void kernel_launch(void* const* d_in, const int* in_sizes, int n_in,
                              void* d_out, int out_size, void* d_ws, size_t ws_size,
                              hipStream_t stream) {
    const int*   idx   = (const int*)d_in[0];
    const float* embed = (const float*)d_in[1];
    const float* enc   = (const float*)d_in[2];
    const float* encv  = (const float*)d_in[3];
    const float* dec   = (const float*)d_in[4];
    const float* lmh   = (const float*)d_in[5];
    const float* freqs = (const float*)d_in[6];
    float* out = (float*)d_out;

    float* rc = (float*)d_ws;                    // T*NN f32
    float* rs = rc + (size_t)T * NN;             // T*NN f32
    short* xT    = (short*)(rs + (size_t)T * NN);    // D*T
    short* x_bf  = xT + (size_t)D * T;               // T*D
    short* xs    = x_bf + (size_t)T * D;             // NH*T*NN
    short* qr    = xs + (size_t)NH * T * NN;         // NH*T*NN
    short* qrT   = qr + (size_t)NH * T * NN;         // NH*NN*T
    short* xy    = qrT + (size_t)NH * NN * T;        // T*NH*NN
    short* Graw  = xy + (size_t)T * NH * NN;         // NH*NC*D*NN
    short* Sp    = Graw + (size_t)NH * NC * D * NN;  // NH*NC*D*NN
    short* encT  = Sp + (size_t)NH * NC * D * NN;    // NH*NN*D
    short* encvT = encT + (size_t)NH * NN * D;       // NH*NN*D
    short* decT  = encvT + (size_t)NH * NN * D;      // [D][NH*NN]
    short* lmhT  = decT + (size_t)D * NH * NN;       // VV*D

    k_wtr<<<dim3(16, 16, 4), 256, 0, stream>>>(enc,  encT, D, NN);
    k_wtr<<<dim3(16, 16, 4), 256, 0, stream>>>(encv, encvT, D, NN);
    k_wtr<<<dim3(64, 16, 1), 256, 0, stream>>>(dec,  decT, NH * NN, D);
    k_wtr<<<dim3(16, 16, 1), 256, 0, stream>>>(lmh,  lmhT, D, VV);
    k_rope<<<T, 256, 0, stream>>>(freqs, rc, rs);
    k_embed<<<T / 32, 256, 0, stream>>>(idx, embed, xT);
    k_tr<<<dim3(T / 64, D / 64, 1), 256, 0, stream>>>(xT, x_bf, D, T);

    for (int l = 0; l < NL; l++) {
        k_encode<<<dim3(T / 32, NH), 256, 0, stream>>>(x_bf, encT, rc, rs, xs, qr);
        k_tr<<<dim3(NN / 64, T / 64, NH), 256, 0, stream>>>(qr, qrT, T, NN);
        k_gram<<<dim3(NN / 64, NC, NH), 256, 0, stream>>>(qrT, xT, Graw);
        k_prefix<<<256, 256, 0, stream>>>(Graw, Sp);
        k_attn<<<dim3(T / 32, NH), 256, 0, stream>>>(qr, xT, Sp, encvT, xs, xy);
        k_mlp<<<T / 16, 256, 0, stream>>>(xy, decT, xT);
        k_tr<<<dim3(T / 64, D / 64, 1), 256, 0, stream>>>(xT, x_bf, D, T);
    }
    k_logits<<<T / 16, 256, 0, stream>>>(x_bf, lmhT, out);
}

// Round 8
// 584.398 us; speedup vs baseline: 3.4948x; 1.0459x over previous
//
#include <hip/hip_runtime.h>
#include <hip/hip_bf16.h>

#define T   4096
#define D   256
#define NH  4
#define NN  256
#define NL  4
#define VV  256
#define CI  128
#define NC  (T/CI)   // 32

typedef short bf16x4 __attribute__((ext_vector_type(4)));
typedef short bf16x8 __attribute__((ext_vector_type(8)));
typedef float f32x4  __attribute__((ext_vector_type(4)));

__device__ __forceinline__ short f2bf(float f) {
    union { float f; unsigned u; } v; v.f = f;
    unsigned r = v.u + 0x7fffu + ((v.u >> 16) & 1u);
    return (short)(r >> 16);
}
__device__ __forceinline__ float bf2f(short s) {
    union { unsigned u; float f; } v; v.u = ((unsigned)(unsigned short)s) << 16;
    return v.f;
}
__device__ __forceinline__ f32x4 mfma16(bf16x8 a, bf16x8 b, f32x4 c) {
    return __builtin_amdgcn_mfma_f32_16x16x32_bf16(a, b, c, 0, 0, 0);
}

// ---------- weight prep: dst[b][c][r] = bf16(src[b][r][c]) ----------
__global__ void __launch_bounds__(256) k_wtr(const float* __restrict__ src,
                                             short* __restrict__ dst, int R, int C) {
    int b = blockIdx.z, r0 = blockIdx.x * 16, c0 = blockIdx.y * 16;
    int i = threadIdx.x >> 4, j = threadIdx.x & 15;
    __shared__ float tile[16][17];
    tile[i][j] = src[((size_t)b * R + r0 + i) * C + c0 + j];
    __syncthreads();
    dst[((size_t)b * C + c0 + i) * R + r0 + j] = f2bf(tile[j][i]);
}

// ---------- rope tables (row-major [t][n]) ----------
__global__ void k_rope(const float* __restrict__ freqs,
                       float* __restrict__ rcos, float* __restrict__ rsin) {
    int t = blockIdx.x, n = threadIdx.x;
    float p = (float)t * freqs[n];
    float fr = p - floorf(p);
    float ang = fr * 6.283185307179586f;
    rcos[(size_t)t * NN + n] = cosf(ang);
    rsin[(size_t)t * NN + n] = sinf(ang);
}

// ---------- embed + LN -> xT (bf16 [D][T]) ----------
__global__ void __launch_bounds__(256) k_embed(const int* __restrict__ idx,
                                               const float* __restrict__ embed,
                                               short* __restrict__ xT) {
    int t0 = blockIdx.x * 32, tid = threadIdx.x;
    __shared__ float ld[32][257];
    __shared__ int ridx[32];
    __shared__ float mu_s[32], rs_s[32];
    if (tid < 32) ridx[tid] = idx[t0 + tid];
    __syncthreads();
    for (int k = 0; k < 32; k++) ld[k][tid] = embed[(size_t)ridx[k] * D + tid];
    __syncthreads();
    int r = tid >> 3, l8 = tid & 7;
    float s = 0.f, q = 0.f;
    for (int d = l8; d < D; d += 8) { float v = ld[r][d]; s += v; q += v * v; }
#pragma unroll
    for (int m = 1; m < 8; m <<= 1) { s += __shfl_xor(s, m); q += __shfl_xor(q, m); }
    if (l8 == 0) {
        float mu = s * (1.f / D);
        float var = q * (1.f / D) - mu * mu;
        mu_s[r] = mu; rs_s[r] = rsqrtf(fmaxf(var, 0.f) + 1e-5f);
    }
    __syncthreads();
    short vals[32];
#pragma unroll
    for (int rr = 0; rr < 32; rr++) vals[rr] = f2bf((ld[rr][tid] - mu_s[rr]) * rs_s[rr]);
    bf16x8* p = (bf16x8*)(xT + (size_t)tid * T + t0);
#pragma unroll
    for (int u = 0; u < 4; u++) p[u] = *(bf16x8*)&vals[u * 8];
}

// ---------- generic bf16 transpose: src[z][R][C] -> dst[z][C][R] ----------
__global__ void __launch_bounds__(256) k_tr(const short* __restrict__ src,
                                            short* __restrict__ dst, int R, int C) {
    int z = blockIdx.z;
    int c0 = blockIdx.x * 64, r0 = blockIdx.y * 64;
    int tid = threadIdx.x;
    __shared__ short ld[64][72];
    const short* s = src + (size_t)z * R * C;
    short* d = dst + (size_t)z * R * C;
    {
        int i = tid >> 2, c4 = (tid & 3) * 16;
        const bf16x8* p = (const bf16x8*)(s + (size_t)(r0 + i) * C + c0 + c4);
        bf16x8 v0 = p[0], v1 = p[1];
        int sw = (i & 7) << 3;
        *(bf16x8*)&ld[i][c4 ^ sw] = v0;
        *(bf16x8*)&ld[i][(c4 + 8) ^ sw] = v1;
    }
    __syncthreads();
    {
        int j = tid >> 2, r4 = (tid & 3) * 16;
        short vals[16];
#pragma unroll
        for (int m = 0; m < 16; m++) vals[m] = ld[r4 + m][j ^ ((m & 7) << 3)];
        bf16x8* q = (bf16x8*)(d + (size_t)(c0 + j) * R + r0 + r4);
        q[0] = *(bf16x8*)&vals[0];
        q[1] = *(bf16x8*)&vals[8];
    }
}

// ---------- encode (swapped): C[n][t] = encT @ x^T; xs=relu, qr=rope ----------
__global__ void __launch_bounds__(256) k_encode(const short* __restrict__ x_bf,
                                                const short* __restrict__ encT,
                                                const float* __restrict__ rc,
                                                const float* __restrict__ rs,
                                                short* __restrict__ xs,
                                                short* __restrict__ qr) {
    int h = blockIdx.y, t0 = blockIdx.x * 32;
    int tid = threadIdx.x, w = tid >> 6, l = tid & 63;
    int l15 = l & 15, lk = (l >> 4) * 8, lr4 = (l >> 4) * 4;
    int nstrip = w * 64;
    const short* ebase = encT + ((size_t)h * NN + nstrip + l15) * D + lk;
    const short* xbase = x_bf + (size_t)(t0 + l15) * D + lk;
    f32x4 acc[4][2];
#pragma unroll
    for (int rt = 0; rt < 4; rt++)
#pragma unroll
        for (int tt = 0; tt < 2; tt++) acc[rt][tt] = (f32x4){0.f, 0.f, 0.f, 0.f};
    for (int k0 = 0; k0 < D; k0 += 32) {
        bf16x8 a[4], b[2];
#pragma unroll
        for (int rt = 0; rt < 4; rt++) a[rt] = *(const bf16x8*)(ebase + rt * 16 * D + k0);
#pragma unroll
        for (int tt = 0; tt < 2; tt++) b[tt] = *(const bf16x8*)(xbase + tt * 16 * D + k0);
#pragma unroll
        for (int rt = 0; rt < 4; rt++)
#pragma unroll
            for (int tt = 0; tt < 2; tt++) acc[rt][tt] = mfma16(a[rt], b[tt], acc[rt][tt]);
    }
#pragma unroll
    for (int rt = 0; rt < 4; rt++)
#pragma unroll
        for (int tt = 0; tt < 2; tt++) {
            int t = t0 + tt * 16 + l15;
            int n0 = nstrip + rt * 16 + lr4;
            float v[4], rot[4];
#pragma unroll
            for (int r = 0; r < 4; r++) v[r] = fmaxf(acc[rt][tt][r], 0.f);
            rot[0] = -v[1]; rot[1] = v[0]; rot[2] = -v[3]; rot[3] = v[2];
            bf16x4 xsv;
#pragma unroll
            for (int r = 0; r < 4; r++) xsv[r] = f2bf(v[r]);
            *(bf16x4*)(xs + ((size_t)h * T + t) * NN + n0) = xsv;
            float4 cv = *(const float4*)(rc + (size_t)t * NN + n0);
            float4 sv = *(const float4*)(rs + (size_t)t * NN + n0);
            float cc[4] = {cv.x, cv.y, cv.z, cv.w}, ss[4] = {sv.x, sv.y, sv.z, sv.w};
            bf16x4 qv;
#pragma unroll
            for (int r = 0; r < 4; r++) qv[r] = f2bf(v[r] * cc[r] + rot[r] * ss[r]);
            *(bf16x4*)(qr + ((size_t)h * T + t) * NN + n0) = qv;
        }
}

// ---------- gram: C[n][d] = qrT_chunk @ xT_chunk^T -> Graw[h][c][d][n] bf16 ----------
__global__ void __launch_bounds__(256) k_gram(const short* __restrict__ qrT,
                                              const short* __restrict__ xT,
                                              short* __restrict__ Graw) {
    int h = blockIdx.z, c = blockIdx.y, n0 = blockIdx.x * 64;
    int tid = threadIdx.x, w = tid >> 6, l = tid & 63;
    int l15 = l & 15, lk = (l >> 4) * 8, lr4 = (l >> 4) * 4;
    const short* abase = qrT + ((size_t)h * NN + n0 + w * 16 + l15) * T + (size_t)c * CI + lk;
    const short* bbase = xT + (size_t)l15 * T + (size_t)c * CI + lk;
    f32x4 acc[16];
#pragma unroll
    for (int dt = 0; dt < 16; dt++) acc[dt] = (f32x4){0.f, 0.f, 0.f, 0.f};
#pragma unroll
    for (int ki = 0; ki < CI / 32; ki++) {
        int k0 = ki * 32;
        bf16x8 a = *(const bf16x8*)(abase + k0);
#pragma unroll
        for (int dt = 0; dt < 16; dt++) {
            bf16x8 b = *(const bf16x8*)(bbase + (size_t)dt * 16 * T + k0);
            acc[dt] = mfma16(a, b, acc[dt]);
        }
    }
#pragma unroll
    for (int dt = 0; dt < 16; dt++) {
        int d = dt * 16 + l15;
        bf16x4 o;
#pragma unroll
        for (int r = 0; r < 4; r++) o[r] = f2bf(acc[dt][r]);
        *(bf16x4*)(Graw + (((size_t)h * NC + c) * D + d) * NN + n0 + w * 16 + lr4) = o;
    }
}

// ---------- exclusive prefix over chunks: Sp[c] = sum_{c'<c} Graw[c'] ----------
__global__ void __launch_bounds__(256) k_prefix(const short* __restrict__ Graw,
                                                short* __restrict__ Sp) {
    int pos = (blockIdx.x * 256 + threadIdx.x) * 4;
    int h = pos >> 16;
    int rem = pos & 65535;
    float run[4] = {0.f, 0.f, 0.f, 0.f};
    for (int c = 0; c < NC; c++) {
        size_t ix = ((size_t)h * NC + c) * 65536 + rem;
        bf16x4 g = *(const bf16x4*)(Graw + ix);
        bf16x4 o;
#pragma unroll
        for (int e = 0; e < 4; e++) { o[e] = f2bf(run[e]); run[e] += bf2f(g[e]); }
        *(bf16x4*)(Sp + ix) = o;
    }
}

// ---------- attn: 64 t-rows per block, 512 threads (8 waves: 4 row-tiles x 2 d-halves).
// yKV = LN(QR@S + tril_strict(QR@QRc^T)@x_c); ys = relu(yKV@encv); xy = xs*ys
__global__ void __launch_bounds__(512) k_attn(const short* __restrict__ qr,
                                              const short* __restrict__ xT,
                                              const short* __restrict__ Sp,
                                              const short* __restrict__ encvT,
                                              const short* __restrict__ xs,
                                              short* __restrict__ xy) {
    int h = blockIdx.y, t0 = blockIdx.x * 64;
    int c = t0 >> 7, cl0 = t0 & 127;          // 0 or 64
    int tid = threadIdx.x, w = tid >> 6, l = tid & 63;
    int l15 = l & 15, lk = (l >> 4) * 8, lr4 = (l >> 4) * 4;
    int rt = w & 3, dh = w >> 2;
    int ntiles = (((cl0 >> 4) + rt) | 1) + 1;   // even, 2..8: P col-tiles this row-tile needs
    __shared__ short P_lds[64][136];            // stride 136 (68 dw = 4 mod 32) -> 2-way, free
    __shared__ short ynorm[64 * 256];           // row-XOR swizzled
    __shared__ float lnb[2][64][2];
    const short* qa  = qr + ((size_t)h * T + t0 + rt * 16 + l15) * NN + lk;  // own 16 rows
    const short* qpb = qr + ((size_t)h * T + (size_t)c * CI + l15) * NN + lk; // chunk rows
    const short* sb  = Sp + (((size_t)h * NC + c) * D + dh * 128 + l15) * NN + lk;
    f32x4 akv[8], ap[4];
#pragma unroll
    for (int dt = 0; dt < 8; dt++) akv[dt] = (f32x4){0.f, 0.f, 0.f, 0.f};
#pragma unroll
    for (int ji = 0; ji < 4; ji++) ap[ji] = (f32x4){0.f, 0.f, 0.f, 0.f};
    for (int k0 = 0; k0 < NN; k0 += 32) {
        bf16x8 a = *(const bf16x8*)(qa + k0);
#pragma unroll
        for (int dt = 0; dt < 8; dt++) {
            bf16x8 bs = *(const bf16x8*)(sb + (size_t)dt * 16 * NN + k0);
            akv[dt] = mfma16(a, bs, akv[dt]);
        }
#pragma unroll
        for (int ji = 0; ji < 4; ji++) {
            int jt = ji * 2 + dh;               // parity-split P tiles across d-half waves
            if (jt < ntiles) {
                bf16x8 bp = *(const bf16x8*)(qpb + (size_t)jt * 16 * NN + k0);
                ap[ji] = mfma16(a, bp, ap[ji]);
            }
        }
    }
#pragma unroll
    for (int ji = 0; ji < 4; ji++) {
        int jt = ji * 2 + dh;
        if (jt < ntiles) {
#pragma unroll
            for (int r = 0; r < 4; r++) {
                int lrow = rt * 16 + lr4 + r;   // block-local row
                int jcl  = jt * 16 + l15;       // chunk-local col
                float pv = (jcl < cl0 + lrow) ? ap[ji][r] : 0.f;  // strict tril (k=-1)
                P_lds[lrow][jcl] = f2bf(pv);
            }
        }
    }
    __syncthreads();
    // intra apply: akv += P @ x_c  (K = ntiles*16, zero-padded to 32-multiple)
    int ksteps = ntiles >> 1;                   // 1..4
#pragma unroll
    for (int ki = 0; ki < 4; ki++) {
        if (ki < ksteps) {
            bf16x8 a = *(const bf16x8*)&P_lds[rt * 16 + l15][ki * 32 + lk];
#pragma unroll
            for (int dt = 0; dt < 8; dt++) {
                bf16x8 b = *(const bf16x8*)(xT + (size_t)(dh * 128 + dt * 16 + l15) * T
                                            + (size_t)c * CI + ki * 32 + lk);
                akv[dt] = mfma16(a, b, akv[dt]);
            }
        }
    }
    // LayerNorm over d (each wave owns 128 of 256 cols for its 16 rows)
    float s[4], q[4], mu[4], rstd[4];
#pragma unroll
    for (int r = 0; r < 4; r++) { s[r] = 0.f; q[r] = 0.f; }
#pragma unroll
    for (int dt = 0; dt < 8; dt++)
#pragma unroll
        for (int r = 0; r < 4; r++) { float v = akv[dt][r]; s[r] += v; q[r] += v * v; }
#pragma unroll
    for (int m = 1; m < 16; m <<= 1)
#pragma unroll
        for (int r = 0; r < 4; r++) { s[r] += __shfl_xor(s[r], m); q[r] += __shfl_xor(q[r], m); }
    if (l15 == 0) {
#pragma unroll
        for (int r = 0; r < 4; r++) {
            int lrow = rt * 16 + lr4 + r;
            lnb[dh][lrow][0] = s[r]; lnb[dh][lrow][1] = q[r];
        }
    }
    __syncthreads();
#pragma unroll
    for (int r = 0; r < 4; r++) {
        int lrow = rt * 16 + lr4 + r;
        float st = lnb[0][lrow][0] + lnb[1][lrow][0];
        float qt = lnb[0][lrow][1] + lnb[1][lrow][1];
        float m_ = st * (1.f / D);
        float var = qt * (1.f / D) - m_ * m_;
        mu[r] = m_; rstd[r] = rsqrtf(fmaxf(var, 0.f) + 1e-5f);
    }
#pragma unroll
    for (int dt = 0; dt < 8; dt++)
#pragma unroll
        for (int r = 0; r < 4; r++) {
            int lrow = rt * 16 + lr4 + r;
            int dcol = dh * 128 + dt * 16 + l15;
            ynorm[lrow * 256 + (dcol ^ ((lrow & 7) << 3))] = f2bf((akv[dt][r] - mu[r]) * rstd[r]);
        }
    __syncthreads();
    // ys (swapped): C[n][t] = encvT @ ynorm^T ; wave w covers 32 n x 64 t
    int nstrip = w * 32;
    f32x4 a2[2][4];
#pragma unroll
    for (int nt = 0; nt < 2; nt++)
#pragma unroll
        for (int tt = 0; tt < 4; tt++) a2[nt][tt] = (f32x4){0.f, 0.f, 0.f, 0.f};
    const short* ev = encvT + ((size_t)h * NN + nstrip + l15) * D + lk;
    for (int k0 = 0; k0 < D; k0 += 32) {
        bf16x8 av[2], bv[4];
#pragma unroll
        for (int nt = 0; nt < 2; nt++) av[nt] = *(const bf16x8*)(ev + nt * 16 * D + k0);
#pragma unroll
        for (int tt = 0; tt < 4; tt++) {
            int row = tt * 16 + l15;
            bv[tt] = *(const bf16x8*)&ynorm[row * 256 + ((k0 + lk) ^ ((l15 & 7) << 3))];
        }
#pragma unroll
        for (int nt = 0; nt < 2; nt++)
#pragma unroll
            for (int tt = 0; tt < 4; tt++) a2[nt][tt] = mfma16(av[nt], bv[tt], a2[nt][tt]);
    }
#pragma unroll
    for (int nt = 0; nt < 2; nt++)
#pragma unroll
        for (int tt = 0; tt < 4; tt++) {
            int n0 = nstrip + nt * 16 + lr4;
            int t = t0 + tt * 16 + l15;
            bf16x4 g = *(const bf16x4*)(xs + ((size_t)h * T + t) * NN + n0);
            bf16x4 o;
#pragma unroll
            for (int r = 0; r < 4; r++) o[r] = f2bf(fmaxf(a2[nt][tt][r], 0.f) * bf2f(g[r]));
            *(bf16x4*)(xy + (size_t)t * (NH * NN) + h * NN + n0) = o;
        }
}

// ---------- mlp: yMLP = xy @ dec; x = LN(x + LN(yMLP)); writes xT in-place ----------
__global__ void __launch_bounds__(256) k_mlp(const short* __restrict__ xy,
                                             const short* __restrict__ decT,
                                             short* __restrict__ xT) {
    int t0 = blockIdx.x * 16;
    int tid = threadIdx.x, w = tid >> 6, l = tid & 63;
    int l15 = l & 15, lk = (l >> 4) * 8, lr4 = (l >> 4) * 4;
    __shared__ float lnb[4][16][2];
    const short* abase = xy + (size_t)(t0 + l15) * (NH * NN) + lk;
    const short* bbase = decT + (size_t)(w * 64 + l15) * (NH * NN) + lk;
    f32x4 acc[4];
#pragma unroll
    for (int dt = 0; dt < 4; dt++) acc[dt] = (f32x4){0.f, 0.f, 0.f, 0.f};
    for (int k0 = 0; k0 < NH * NN; k0 += 32) {
        bf16x8 a = *(const bf16x8*)(abase + k0);
#pragma unroll
        for (int dt = 0; dt < 4; dt++) {
            bf16x8 b = *(const bf16x8*)(bbase + (size_t)dt * 16 * (NH * NN) + k0);
            acc[dt] = mfma16(a, b, acc[dt]);
        }
    }
    float s[4], q[4];
#pragma unroll
    for (int r = 0; r < 4; r++) { s[r] = 0.f; q[r] = 0.f; }
#pragma unroll
    for (int dt = 0; dt < 4; dt++)
#pragma unroll
        for (int r = 0; r < 4; r++) { float v = acc[dt][r]; s[r] += v; q[r] += v * v; }
#pragma unroll
    for (int m = 1; m < 16; m <<= 1)
#pragma unroll
        for (int r = 0; r < 4; r++) { s[r] += __shfl_xor(s[r], m); q[r] += __shfl_xor(q[r], m); }
    if (l15 == 0)
#pragma unroll
        for (int r = 0; r < 4; r++) { lnb[w][lr4 + r][0] = s[r]; lnb[w][lr4 + r][1] = q[r]; }
    __syncthreads();
    float mu1[4], rstd1[4];
#pragma unroll
    for (int r = 0; r < 4; r++) {
        float st = 0.f, qt = 0.f;
#pragma unroll
        for (int ww = 0; ww < 4; ww++) { st += lnb[ww][lr4 + r][0]; qt += lnb[ww][lr4 + r][1]; }
        float m_ = st * (1.f / D);
        float var = qt * (1.f / D) - m_ * m_;
        mu1[r] = m_; rstd1[r] = rsqrtf(fmaxf(var, 0.f) + 1e-5f);
    }
    float z[4][4];
#pragma unroll
    for (int dt = 0; dt < 4; dt++) {
        bf16x4 xo = *(const bf16x4*)(xT + (size_t)(w * 64 + dt * 16 + l15) * T + t0 + lr4);
#pragma unroll
        for (int r = 0; r < 4; r++)
            z[dt][r] = bf2f(xo[r]) + (acc[dt][r] - mu1[r]) * rstd1[r];
    }
#pragma unroll
    for (int r = 0; r < 4; r++) { s[r] = 0.f; q[r] = 0.f; }
#pragma unroll
    for (int dt = 0; dt < 4; dt++)
#pragma unroll
        for (int r = 0; r < 4; r++) { float v = z[dt][r]; s[r] += v; q[r] += v * v; }
#pragma unroll
    for (int m = 1; m < 16; m <<= 1)
#pragma unroll
        for (int r = 0; r < 4; r++) { s[r] += __shfl_xor(s[r], m); q[r] += __shfl_xor(q[r], m); }
    __syncthreads();
    if (l15 == 0)
#pragma unroll
        for (int r = 0; r < 4; r++) { lnb[w][lr4 + r][0] = s[r]; lnb[w][lr4 + r][1] = q[r]; }
    __syncthreads();
#pragma unroll
    for (int r = 0; r < 4; r++) {
        float st = 0.f, qt = 0.f;
#pragma unroll
        for (int ww = 0; ww < 4; ww++) { st += lnb[ww][lr4 + r][0]; qt += lnb[ww][lr4 + r][1]; }
        float m_ = st * (1.f / D);
        float var = qt * (1.f / D) - m_ * m_;
        mu1[r] = m_; rstd1[r] = rsqrtf(fmaxf(var, 0.f) + 1e-5f);
    }
#pragma unroll
    for (int dt = 0; dt < 4; dt++) {
        bf16x4 o;
#pragma unroll
        for (int r = 0; r < 4; r++) o[r] = f2bf((z[dt][r] - mu1[r]) * rstd1[r]);
        *(bf16x4*)(xT + (size_t)(w * 64 + dt * 16 + l15) * T + t0 + lr4) = o;
    }
}

// ---------- logits (swapped): C[v][t] = lmhT @ x^T -> out[t][v] f32 ----------
__global__ void __launch_bounds__(256) k_logits(const short* __restrict__ x_bf,
                                                const short* __restrict__ lmhT,
                                                float* __restrict__ out) {
    int t0 = blockIdx.x * 16;
    int tid = threadIdx.x, w = tid >> 6, l = tid & 63;
    int l15 = l & 15, lk = (l >> 4) * 8, lr4 = (l >> 4) * 4;
    const short* ab = lmhT + (size_t)(w * 64 + l15) * D + lk;
    const short* bb = x_bf + (size_t)(t0 + l15) * D + lk;
    f32x4 acc[4];
#pragma unroll
    for (int vt = 0; vt < 4; vt++) acc[vt] = (f32x4){0.f, 0.f, 0.f, 0.f};
    for (int k0 = 0; k0 < D; k0 += 32) {
        bf16x8 b = *(const bf16x8*)(bb + k0);
#pragma unroll
        for (int vt = 0; vt < 4; vt++) {
            bf16x8 a = *(const bf16x8*)(ab + (size_t)vt * 16 * D + k0);
            acc[vt] = mfma16(a, b, acc[vt]);
        }
    }
#pragma unroll
    for (int vt = 0; vt < 4; vt++) {
        int t = t0 + l15;
        int v0 = w * 64 + vt * 16 + lr4;
        *(f32x4*)(out + (size_t)t * VV + v0) = acc[vt];
    }
}

// ---------- launch ----------
extern "C" void kernel_launch(void* const* d_in, const int* in_sizes, int n_in,
                              void* d_out, int out_size, void* d_ws, size_t ws_size,
                              hipStream_t stream) {
    const int*   idx   = (const int*)d_in[0];
    const float* embed = (const float*)d_in[1];
    const float* enc   = (const float*)d_in[2];
    const float* encv  = (const float*)d_in[3];
    const float* dec   = (const float*)d_in[4];
    const float* lmh   = (const float*)d_in[5];
    const float* freqs = (const float*)d_in[6];
    float* out = (float*)d_out;

    float* rc = (float*)d_ws;                    // T*NN f32
    float* rs = rc + (size_t)T * NN;             // T*NN f32
    short* xT    = (short*)(rs + (size_t)T * NN);    // D*T
    short* x_bf  = xT + (size_t)D * T;               // T*D
    short* xs    = x_bf + (size_t)T * D;             // NH*T*NN
    short* qr    = xs + (size_t)NH * T * NN;         // NH*T*NN
    short* qrT   = qr + (size_t)NH * T * NN;         // NH*NN*T
    short* xy    = qrT + (size_t)NH * NN * T;        // T*NH*NN
    short* Graw  = xy + (size_t)T * NH * NN;         // NH*NC*D*NN (16.8 MB)
    short* Sp    = Graw + (size_t)NH * NC * D * NN;  // NH*NC*D*NN
    short* encT  = Sp + (size_t)NH * NC * D * NN;    // NH*NN*D
    short* encvT = encT + (size_t)NH * NN * D;       // NH*NN*D
    short* decT  = encvT + (size_t)NH * NN * D;      // [D][NH*NN]
    short* lmhT  = decT + (size_t)D * NH * NN;       // VV*D

    k_wtr<<<dim3(16, 16, 4), 256, 0, stream>>>(enc,  encT, D, NN);
    k_wtr<<<dim3(16, 16, 4), 256, 0, stream>>>(encv, encvT, D, NN);
    k_wtr<<<dim3(64, 16, 1), 256, 0, stream>>>(dec,  decT, NH * NN, D);
    k_wtr<<<dim3(16, 16, 1), 256, 0, stream>>>(lmh,  lmhT, D, VV);
    k_rope<<<T, 256, 0, stream>>>(freqs, rc, rs);
    k_embed<<<T / 32, 256, 0, stream>>>(idx, embed, xT);
    k_tr<<<dim3(T / 64, D / 64, 1), 256, 0, stream>>>(xT, x_bf, D, T);

    for (int l = 0; l < NL; l++) {
        k_encode<<<dim3(T / 32, NH), 256, 0, stream>>>(x_bf, encT, rc, rs, xs, qr);
        k_tr<<<dim3(NN / 64, T / 64, NH), 256, 0, stream>>>(qr, qrT, T, NN);
        k_gram<<<dim3(NN / 64, NC, NH), 256, 0, stream>>>(qrT, xT, Graw);
        k_prefix<<<256, 256, 0, stream>>>(Graw, Sp);
        k_attn<<<dim3(T / 64, NH), 512, 0, stream>>>(qr, xT, Sp, encvT, xs, xy);
        k_mlp<<<T / 16, 256, 0, stream>>>(xy, decT, xT);
        k_tr<<<dim3(T / 64, D / 64, 1), 256, 0, stream>>>(xT, x_bf, D, T);
    }
    k_logits<<<T / 16, 256, 0, stream>>>(x_bf, lmhT, out);
}